// Round 14
// baseline (1335.903 us; speedup 1.0000x reference)
//
#include <hip/hip_runtime.h>
#include <cstdio>
#include <cstdint>

typedef unsigned short u16;
typedef __bf16 bf16x8 __attribute__((ext_vector_type(8)));
typedef float f32x4 __attribute__((ext_vector_type(4)));

// problem constants
static const int EE = 1024;   // embed
static const int TT = 1024;   // seq len
static const int BB = 2;      // batch
static const int NTOK = 2048; // B*T
static const int HH = 16;     // heads
static const int DK = 64;
static const int FF = 4096;
static const int VV = 32000;
static const int LL = 6;

__device__ __forceinline__ float bf2f(u16 u) {
  unsigned int i = ((unsigned int)u) << 16;
  float f; __builtin_memcpy(&f, &i, 4); return f;
}
__device__ __forceinline__ u16 f2bf(float f) {
  unsigned int i; __builtin_memcpy(&i, &f, 4);
  unsigned int r = i + 0x7fffu + ((i >> 16) & 1u);
  return (u16)(r >> 16);
}

__device__ __forceinline__ void gll16(const u16* g, u16* l) {
  __builtin_amdgcn_global_load_lds(
      (__attribute__((address_space(1))) void*)(uintptr_t)g,
      (__attribute__((address_space(3))) void*)l,
      16, 0, 0);
}

// ---------------- fused embed + first layernorm ----------------
__global__ __launch_bounds__(256) void embed_ln_k(const int* __restrict__ idx,
                                                  const float* __restrict__ emb,
                                                  const float* __restrict__ pos,
                                                  float* __restrict__ x,
                                                  const float* __restrict__ g,
                                                  const float* __restrict__ b,
                                                  u16* __restrict__ out) {
  int row = blockIdx.x * 4 + (threadIdx.x >> 6);
  int lane = threadIdx.x & 63;
  long base = (long)row * EE;
  int tok = idx[row];
  int t = row & (TT - 1);
  const float* er = emb + (long)tok * EE;
  const float* pr = pos + (long)t * EE;
  float v[16];
  float s = 0.f, s2 = 0.f;
#pragma unroll
  for (int j = 0; j < 16; j++) {
    int c = j * 64 + lane;
    float tv = er[c] + pr[c];
    x[base + c] = tv;
    v[j] = tv; s += tv; s2 += tv * tv;
  }
#pragma unroll
  for (int o = 32; o; o >>= 1) { s += __shfl_xor(s, o); s2 += __shfl_xor(s2, o); }
  float mu = s * (1.f / EE);
  float var = s2 * (1.f / EE) - mu * mu;
  float rs = rsqrtf(var + 1e-5f);
  u16* orow = out + base;
#pragma unroll
  for (int j = 0; j < 16; j++) {
    int c = j * 64 + lane;
    orow[c] = f2bf((v[j] - mu) * rs * g[c] + b[c]);
  }
}

// ---------------- fused residual-reduce + layernorm (bf16 partials) ----------------
template <int NS>
__global__ __launch_bounds__(256) void ln_fused_k(float* __restrict__ x,
                                                  const u16* __restrict__ part, long pstride,
                                                  const float* __restrict__ bias,
                                                  const float* __restrict__ g,
                                                  const float* __restrict__ b,
                                                  u16* __restrict__ out) {
  int row = blockIdx.x * 4 + (threadIdx.x >> 6);
  int lane = threadIdx.x & 63;
  long base = (long)row * EE;
  float v[16];
  float s = 0.f, s2 = 0.f;
#pragma unroll
  for (int j = 0; j < 16; j++) {
    int c = j * 64 + lane;
    float t = x[base + c];
    if constexpr (NS > 0) {
      t += bias[c];
#pragma unroll
      for (int p = 0; p < NS; p++) t += bf2f(part[(long)p * pstride + base + c]);
      x[base + c] = t;
    }
    v[j] = t; s += t; s2 += t * t;
  }
#pragma unroll
  for (int o = 32; o; o >>= 1) { s += __shfl_xor(s, o); s2 += __shfl_xor(s2, o); }
  float mu = s * (1.f / EE);
  float var = s2 * (1.f / EE) - mu * mu;
  float rs = rsqrtf(var + 1e-5f);
  u16* orow = out + base;
#pragma unroll
  for (int j = 0; j < 16; j++) {
    int c = j * 64 + lane;
    orow[c] = f2bf((v[j] - mu) * rs * g[c] + b[c]);
  }
}

// ---------------- pack Wq/Wk/Wv (ALL layers) into bf16 B^T [L][3072][1024] ----------------
__global__ __launch_bounds__(256) void pack_qkvT_k(const float* __restrict__ Wq,
                                                   const float* __restrict__ Wk,
                                                   const float* __restrict__ Wv,
                                                   u16* __restrict__ out) {
  int l = blockIdx.y;
  const float* Wq_l = Wq + (size_t)l * HH * EE * DK;
  const float* Wk_l = Wk + (size_t)l * HH * EE * DK;
  const float* Wv_l = Wv + (size_t)l * HH * EE * DK;
  u16* out_l = out + (size_t)l * 3 * EE * EE;
  long base = ((long)blockIdx.x * 256 + threadIdx.x) * 4;
  int c = (int)(base >> 10);
  int e0 = (int)(base & 1023);
  const float* W = (c < 1024) ? Wq_l : (c < 2048 ? Wk_l : Wv_l);
  int cm = c & 1023;
  int hh = cm >> 6, d = cm & 63;
#pragma unroll
  for (int i = 0; i < 4; i++) {
    int e = e0 + i;
    out_l[(long)c * EE + e] = f2bf(W[((long)hh * EE + e) * DK + d]);
  }
}

// ---------------- batched transpose: src[R,C] (f32 or bf16) -> bf16 dst[C,R] ----------------
template <typename ST>
__global__ __launch_bounds__(256) void transpose_to_bf16(const ST* __restrict__ src,
                                                         long s_z1, long s_z2, int zmod, int ld_s,
                                                         u16* __restrict__ dst,
                                                         long d_z, int ld_d, int R, int C) {
  __shared__ u16 t[32][33];
  int z = blockIdx.z;
  const ST* S = src + (z / zmod) * s_z1 + (z % zmod) * s_z2;
  u16* D = dst + (long)z * d_z;
  int c0 = blockIdx.x * 32, r0 = blockIdx.y * 32;
  int lx = threadIdx.x & 31, ly = threadIdx.x >> 5;
#pragma unroll
  for (int i = 0; i < 4; i++) {
    int r = r0 + ly + i * 8;
    ST val = S[(long)r * ld_s + c0 + lx];
    if constexpr (sizeof(ST) == 4) t[ly + i * 8][lx] = f2bf((float)val);
    else t[ly + i * 8][lx] = (u16)val;
  }
  __syncthreads();
#pragma unroll
  for (int i = 0; i < 4; i++) {
    int c = c0 + ly + i * 8;
    D[(long)c * ld_d + r0 + lx] = t[lx][ly + i * 8];
  }
}

// ---------------- fused flash attention (one 64-row q-tile per block) ----------------
// grid (16, 32), 256 thr. jq = 15 - blockIdx.x (longest tiles dispatch first, LPT).
// 512 blocks -> 2 blocks/CU co-resident (LDS 54 KB); dynamic scheduling balances.
__global__ __launch_bounds__(256) void flash_attn_k(const u16* __restrict__ qkv,
                                                    const u16* __restrict__ vT,
                                                    u16* __restrict__ o) {
  __shared__ u16 Qs[64 * 72];
  __shared__ u16 Ks[2][64 * 72];
  __shared__ u16 Vs[2][64 * 72];
  __shared__ u16 Ps[4][16 * 72];

  int tid = threadIdx.x;
  int lane = tid & 63, w = tid >> 6;
  int fr = lane & 15, kg = lane >> 4;
  int z = blockIdx.y;
  int b = z >> 4, h = z & 15;
  const u16* qbase = qkv + (long)b * TT * 3072 + h * 64;
  const u16* kbase = qbase + 1024;
  const u16* vbase = vT + (long)z * DK * TT;  // [d][t]
  const float scale = 0.03125f;  // 1/sqrt(E)

  int jq = 15 - (int)blockIdx.x;
  int q0 = jq * 64;
  int nt = jq + 1;

  int4 kreg[2], vreg[2];
#pragma unroll
  for (int i = 0; i < 2; i++) {
    int c = i * 256 + tid, row = c >> 3, c8 = c & 7;
    *(int4*)&Qs[row * 72 + c8 * 8] = *(const int4*)(qbase + (long)(q0 + row) * 3072 + c8 * 8);
    kreg[i] = *(const int4*)(kbase + (long)row * 3072 + c8 * 8);
    vreg[i] = *(const int4*)(vbase + (long)row * TT + c8 * 8);
  }
#pragma unroll
  for (int i = 0; i < 2; i++) {
    int c = i * 256 + tid, row = c >> 3, c8 = c & 7;
    *(int4*)&Ks[0][row * 72 + c8 * 8] = kreg[i];
    *(int4*)&Vs[0][row * 72 + c8 * 8] = vreg[i];
  }
  __syncthreads();

  f32x4 zero = {0.f, 0.f, 0.f, 0.f};
  f32x4 acc_o[4];
  float m_i[4], l_i[4];
#pragma unroll
  for (int n = 0; n < 4; n++) acc_o[n] = zero;
#pragma unroll
  for (int r = 0; r < 4; r++) { m_i[r] = -1e30f; l_i[r] = 0.f; }

  for (int t = 0; t < nt; t++) {
    int cur = t & 1;
    int kv0 = t * 64;
    bool pf = (t + 1 < nt);
    if (pf) {
      int kvn = kv0 + 64;
#pragma unroll
      for (int i = 0; i < 2; i++) {
        int c = i * 256 + tid, row = c >> 3, c8 = c & 7;
        kreg[i] = *(const int4*)(kbase + (long)(kvn + row) * 3072 + c8 * 8);
        vreg[i] = *(const int4*)(vbase + (long)row * TT + kvn + c8 * 8);
      }
    }

    f32x4 s[4];
#pragma unroll
    for (int n = 0; n < 4; n++) s[n] = zero;
    {
      bf16x8 aq[2], bk[4][2];
#pragma unroll
      for (int kk = 0; kk < 2; kk++)
        aq[kk] = *(const bf16x8*)&Qs[(w * 16 + fr) * 72 + kk * 32 + kg * 8];
#pragma unroll
      for (int n = 0; n < 4; n++)
#pragma unroll
        for (int kk = 0; kk < 2; kk++)
          bk[n][kk] = *(const bf16x8*)&Ks[cur][(n * 16 + fr) * 72 + kk * 32 + kg * 8];
#pragma unroll
      for (int kk = 0; kk < 2; kk++)
#pragma unroll
        for (int n = 0; n < 4; n++)
          s[n] = __builtin_amdgcn_mfma_f32_16x16x32_bf16(aq[kk], bk[n][kk], s[n], 0, 0, 0);
    }

    float sv[4][4];
#pragma unroll
    for (int n = 0; n < 4; n++)
#pragma unroll
      for (int r = 0; r < 4; r++) {
        int qg = q0 + w * 16 + kg * 4 + r;
        int kgl = kv0 + n * 16 + fr;
        float val = s[n][r] * scale;
        sv[n][r] = (kgl > qg) ? -1e30f : val;
      }
#pragma unroll
    for (int r = 0; r < 4; r++) {
      float rm = fmaxf(fmaxf(sv[0][r], sv[1][r]), fmaxf(sv[2][r], sv[3][r]));
      rm = fmaxf(rm, __shfl_xor(rm, 1));
      rm = fmaxf(rm, __shfl_xor(rm, 2));
      rm = fmaxf(rm, __shfl_xor(rm, 4));
      rm = fmaxf(rm, __shfl_xor(rm, 8));
      float mn = fmaxf(m_i[r], rm);
      float f = __expf(m_i[r] - mn);
      m_i[r] = mn;
      float rs = 0.f;
#pragma unroll
      for (int n = 0; n < 4; n++) {
        float pv = __expf(sv[n][r] - mn);
        sv[n][r] = pv;
        rs += pv;
      }
      rs += __shfl_xor(rs, 1);
      rs += __shfl_xor(rs, 2);
      rs += __shfl_xor(rs, 4);
      rs += __shfl_xor(rs, 8);
      l_i[r] = l_i[r] * f + rs;
#pragma unroll
      for (int n = 0; n < 4; n++) acc_o[n][r] *= f;
    }
#pragma unroll
    for (int n = 0; n < 4; n++)
#pragma unroll
      for (int r = 0; r < 4; r++)
        Ps[w][(kg * 4 + r) * 72 + n * 16 + fr] = f2bf(sv[n][r]);

    {
      bf16x8 pa[2], bv[4][2];
#pragma unroll
      for (int kk = 0; kk < 2; kk++)
        pa[kk] = *(const bf16x8*)&Ps[w][fr * 72 + kk * 32 + kg * 8];
#pragma unroll
      for (int n = 0; n < 4; n++)
#pragma unroll
        for (int kk = 0; kk < 2; kk++)
          bv[n][kk] = *(const bf16x8*)&Vs[cur][(n * 16 + fr) * 72 + kk * 32 + kg * 8];
#pragma unroll
      for (int kk = 0; kk < 2; kk++)
#pragma unroll
        for (int n = 0; n < 4; n++)
          acc_o[n] = __builtin_amdgcn_mfma_f32_16x16x32_bf16(pa[kk], bv[n][kk], acc_o[n], 0, 0, 0);
    }

    if (pf) {
#pragma unroll
      for (int i = 0; i < 2; i++) {
        int c = i * 256 + tid, row = c >> 3, c8 = c & 7;
        *(int4*)&Ks[cur ^ 1][row * 72 + c8 * 8] = kreg[i];
        *(int4*)&Vs[cur ^ 1][row * 72 + c8 * 8] = vreg[i];
      }
    }
    __syncthreads();
  }

  u16* obase = o + ((long)b * TT + q0) * EE + h * 64;
#pragma unroll
  for (int r = 0; r < 4; r++) {
    float inv = 1.f / l_i[r];
    int qrow = w * 16 + kg * 4 + r;
#pragma unroll
    for (int n = 0; n < 4; n++)
      obase[(long)qrow * EE + n * 16 + fr] = f2bf(acc_o[n][r] * inv);
  }
}

// ---------------- 128x128 NT GEMM, double-buffered counted-vmcnt pipeline ----------------
// EPI: 0 = bf16 C=acc ; 1 = fp32 C=acc+bias ; 2 = bf16 C=relu(acc+bias) ;
//      4 = bf16 C=acc (split-K partial at blockIdx.z * c_zs)
template <int EPI>
__global__ __launch_bounds__(256) void gemm_nt(
    const u16* __restrict__ A, const u16* __restrict__ BT, void* Cv,
    const float* __restrict__ bias,
    int Kc, int lda, int ldb, int ldc, long c_zs) {
  constexpr int BK = 64;
  __shared__ u16 As[2][128 * BK];
  __shared__ u16 Bs[2][128 * BK];

  int m0 = blockIdx.x * 128, n0 = blockIdx.y * 128;
  int z = blockIdx.z;
  int tid = threadIdx.x, lane = tid & 63, wave = tid >> 6;
  int wm = wave >> 1, wn = wave & 1;
  int fr = lane & 15, kg = lane >> 4;
  int xk0 = ((kg) ^ (fr & 7)) * 8;
  int xk1 = ((4 + kg) ^ (fr & 7)) * 8;
  int kbeg = z * Kc;

  auto STAGE = [&](int t, int b) {
    int k0 = kbeg + t * BK;
#pragma unroll
    for (int i = 0; i < 4; i++) {
      int c = i * 256 + tid, row = c >> 3;
      int ch = (c & 7) ^ (row & 7);  // pre-swizzled global source (rule #21)
      gll16(A + (long)(m0 + row) * lda + k0 + ch * 8, &As[b][c * 8]);
      gll16(BT + (long)(n0 + row) * ldb + k0 + ch * 8, &Bs[b][c * 8]);
    }
  };

  f32x4 zero = {0.f, 0.f, 0.f, 0.f};
  f32x4 acc[4][4];
#pragma unroll
  for (int m = 0; m < 4; m++)
#pragma unroll
    for (int n = 0; n < 4; n++) acc[m][n] = zero;

  int NT = Kc / BK;
  STAGE(0, 0);
  if (NT > 1) STAGE(1, 1);

  for (int c = 0; c < NT; c++) {
    if (c + 1 < NT) asm volatile("s_waitcnt vmcnt(8)" ::: "memory");
    else            asm volatile("s_waitcnt vmcnt(0)" ::: "memory");
    __builtin_amdgcn_s_barrier();
    const u16* Ab = As[c & 1];
    const u16* Bb = Bs[c & 1];
#pragma unroll
    for (int kk = 0; kk < 2; kk++) {
      int xo = kk ? xk1 : xk0;
      bf16x8 af[4], bf[4];
#pragma unroll
      for (int m = 0; m < 4; m++)
        af[m] = *(const bf16x8*)&Ab[(wm * 64 + m * 16 + fr) * BK + xo];
#pragma unroll
      for (int n = 0; n < 4; n++)
        bf[n] = *(const bf16x8*)&Bb[(wn * 64 + n * 16 + fr) * BK + xo];
      __builtin_amdgcn_s_setprio(1);
#pragma unroll
      for (int m = 0; m < 4; m++)
#pragma unroll
        for (int n = 0; n < 4; n++)
          acc[m][n] = __builtin_amdgcn_mfma_f32_16x16x32_bf16(af[m], bf[n], acc[m][n], 0, 0, 0);
      __builtin_amdgcn_s_setprio(0);
    }
    __builtin_amdgcn_s_barrier();
    if (c + 2 < NT) STAGE(c + 2, c & 1);
  }

  u16* C16 = (u16*)Cv;
  float* C32 = (float*)Cv;
  long cb = (long)z * c_zs;
  int rowb = m0 + wm * 64, colb = n0 + wn * 64;
#pragma unroll
  for (int m = 0; m < 4; m++) {
#pragma unroll
    for (int n = 0; n < 4; n++) {
      int gc = colb + n * 16 + fr;
      float bv = 0.f;
      if (EPI == 1 || EPI == 2) bv = bias[gc];
#pragma unroll
      for (int r = 0; r < 4; r++) {
        int gr = rowb + m * 16 + kg * 4 + r;
        long ci = cb + (long)gr * ldc + gc;
        float val = acc[m][n][r];
        if (EPI == 0) C16[ci] = f2bf(val);
        else if (EPI == 1) C32[ci] = val + bv;
        else if (EPI == 2) C16[ci] = f2bf(fmaxf(val + bv, 0.f));
        else C16[ci] = f2bf(val);  // EPI 4: bf16 split-K partial
      }
    }
  }
}

// ---------------- 256x256 NT GEMM, 8 waves, coarse counted-vmcnt (R5, converged best) ----------------
// Structure ledger (all refcheck'd on this problem): coarse+vmcnt(8)=183-189us;
// 8-phase variants=194-198; nt-stores=216; 3-stage 256x128 ring=244. Keep coarse.
__global__ __launch_bounds__(512) void gemm256_nt(
    const u16* __restrict__ A, const u16* __restrict__ BT,
    float* __restrict__ C, const float* __restrict__ bias,
    int K, int lda, int ldb, int ldc) {
  __shared__ u16 lds[2][2][256 * 64];

  int tid = threadIdx.x, lane = tid & 63, wave = tid >> 6;
  int wm = wave >> 2, wn = wave & 3;
  int fr = lane & 15, kg = lane >> 4;
  int m0 = blockIdx.x * 256, n0 = blockIdx.y * 256;

  auto STAGE = [&](int t, int b) {
    int k0 = t * 64;
#pragma unroll
    for (int r = 0; r < 4; r++) {
      int g = r * 512 + tid;
      int row = g >> 3, cl = (g & 7) ^ (row & 7);
      gll16(A + (long)(m0 + row) * lda + k0 + cl * 8, &lds[b][0][g * 8]);
    }
#pragma unroll
    for (int r = 0; r < 4; r++) {
      int g = r * 512 + tid;
      int row = g >> 3, cl = (g & 7) ^ (row & 7);
      gll16(BT + (long)(n0 + row) * ldb + k0 + cl * 8, &lds[b][1][g * 8]);
    }
  };

  f32x4 zero = {0.f, 0.f, 0.f, 0.f};
  f32x4 acc[8][4];
#pragma unroll
  for (int m = 0; m < 8; m++)
#pragma unroll
    for (int n = 0; n < 4; n++) acc[m][n] = zero;

  int NT = K / 64;
  STAGE(0, 0);
  if (NT > 1) STAGE(1, 1);

  for (int c = 0; c < NT; c++) {
    if (c + 1 < NT) asm volatile("s_waitcnt vmcnt(8)" ::: "memory");
    else            asm volatile("s_waitcnt vmcnt(0)" ::: "memory");
    __builtin_amdgcn_s_barrier();
    const u16* Ab = lds[c & 1][0];
    const u16* Bb = lds[c & 1][1];
#pragma unroll
    for (int ph = 0; ph < 4; ph++) {
      int mh = ph >> 1, nh = ph & 1;
      bf16x8 af[4][2], bf[2][2];
#pragma unroll
      for (int m = 0; m < 4; m++) {
        int row = wm * 128 + mh * 64 + m * 16 + fr;
#pragma unroll
        for (int kk = 0; kk < 2; kk++) {
          int cp = (kk * 4 + kg) ^ (row & 7);
          af[m][kk] = *(const bf16x8*)&Ab[row * 64 + cp * 8];
        }
      }
#pragma unroll
      for (int n = 0; n < 2; n++) {
        int row = wn * 64 + nh * 32 + n * 16 + fr;
#pragma unroll
        for (int kk = 0; kk < 2; kk++) {
          int cp = (kk * 4 + kg) ^ (row & 7);
          bf[n][kk] = *(const bf16x8*)&Bb[row * 64 + cp * 8];
        }
      }
      __builtin_amdgcn_s_setprio(1);
#pragma unroll
      for (int kk = 0; kk < 2; kk++)
#pragma unroll
        for (int m = 0; m < 4; m++)
#pragma unroll
          for (int n = 0; n < 2; n++)
            acc[mh * 4 + m][nh * 2 + n] = __builtin_amdgcn_mfma_f32_16x16x32_bf16(
                af[m][kk], bf[n][kk], acc[mh * 4 + m][nh * 2 + n], 0, 0, 0);
      __builtin_amdgcn_s_setprio(0);
    }
    __builtin_amdgcn_s_barrier();
    if (c + 2 < NT) STAGE(c + 2, c & 1);
  }

  // epilogue: fp32 + bias (plain stores — nt stores measured WORSE, R8)
  int rowb = m0 + wm * 128, colb = n0 + wn * 64;
#pragma unroll
  for (int m = 0; m < 8; m++) {
#pragma unroll
    for (int n = 0; n < 4; n++) {
      int gc = colb + n * 16 + fr;
      float bv = bias[gc];
#pragma unroll
      for (int r = 0; r < 4; r++) {
        int gr = rowb + m * 16 + kg * 4 + r;
        C[(long)gr * ldc + gc] = acc[m][n][r] + bv;
      }
    }
  }
}

extern "C" void kernel_launch(void* const* d_in, const int* in_sizes, int n_in,
                              void* d_out, int out_size, void* d_ws, size_t ws_size,
                              hipStream_t stream) {
  const int*   idx  = (const int*)d_in[0];
  const float* emb  = (const float*)d_in[1];
  const float* pos  = (const float*)d_in[2];
  const float* Wq   = (const float*)d_in[3];
  const float* Wk   = (const float*)d_in[4];
  const float* Wv   = (const float*)d_in[5];
  const float* Wp   = (const float*)d_in[6];
  const float* bp   = (const float*)d_in[7];
  const float* ln1g = (const float*)d_in[8];
  const float* ln1b = (const float*)d_in[9];
  const float* ln2g = (const float*)d_in[10];
  const float* ln2b = (const float*)d_in[11];
  const float* W1   = (const float*)d_in[12];
  const float* b1   = (const float*)d_in[13];
  const float* W2   = (const float*)d_in[14];
  const float* b2   = (const float*)d_in[15];
  const float* lnfg = (const float*)d_in[16];
  const float* lnfb = (const float*)d_in[17];
  const float* Wout = (const float*)d_in[18];
  const float* bout = (const float*)d_in[19];

  char* w = (char*)d_ws;
  size_t off = 0;
  auto alloc = [&](size_t bytes) {
    void* p = w + off;
    off += (bytes + 255) & ~(size_t)255;
    return p;
  };
  float* x    = (float*)alloc((size_t)NTOK * EE * 4);
  u16* h      = (u16*)alloc((size_t)NTOK * EE * 2);
  u16* qkv    = (u16*)alloc((size_t)NTOK * 3 * EE * 2);
  u16* vT     = (u16*)alloc((size_t)BB * HH * DK * TT * 2);
  u16* big    = (u16*)alloc((size_t)VV * EE * 2);
  u16* o      = (u16*)alloc((size_t)NTOK * EE * 2);
  u16* mid    = (u16*)alloc((size_t)NTOK * FF * 2);
  u16* W1T    = (u16*)alloc((size_t)FF * EE * 2);
  u16* W2T    = (u16*)alloc((size_t)EE * FF * 2);
  u16* pbuf   = (u16*)alloc((size_t)4 * NTOK * EE * 2);  // bf16 split-K partials
  if (off > ws_size) {
    fprintf(stderr, "kernel_launch: ws too small, need %zu have %zu\n", off, ws_size);
    return;
  }
  // optional hoisted per-layer MLP weight transposes (fallback if ws too small)
  size_t off_saved = off;
  u16* W1T_all = (u16*)alloc((size_t)LL * FF * EE * 2);
  u16* W2T_all = (u16*)alloc((size_t)LL * EE * FF * 2);
  bool hoist = (off <= ws_size);
  if (!hoist) off = off_saved;

  u16* WqkvT_all = big;                            // [6][3072][1024] = 36 MB
  u16* WpT_all   = big + (size_t)6 * 3 * EE * EE;  // [6][1024][1024] = 12 MB
  const long PS = (long)NTOK * EE;

  // fused embed + LN(layer 0)
  embed_ln_k<<<NTOK / 4, 256, 0, stream>>>(idx, emb, pos, x, ln1g, ln1b, h);
  pack_qkvT_k<<<dim3(3 * EE * EE / 1024, LL), 256, 0, stream>>>(Wq, Wk, Wv, WqkvT_all);
  transpose_to_bf16<float><<<dim3(32, 32, LL), 256, 0, stream>>>(
      Wp, (long)EE * EE, 0, 1, EE, WpT_all, (long)EE * EE, EE, EE, EE);
  if (hoist) {
    transpose_to_bf16<float><<<dim3(FF / 32, EE / 32, LL), 256, 0, stream>>>(
        W1, (long)EE * FF, 0, 1, FF, W1T_all, (long)FF * EE, EE, EE, FF);
    transpose_to_bf16<float><<<dim3(EE / 32, FF / 32, LL), 256, 0, stream>>>(
        W2, (long)FF * EE, 0, 1, EE, W2T_all, (long)EE * FF, FF, FF, EE);
  }

  for (int l = 0; l < LL; l++) {
    if (l > 0)
      ln_fused_k<4><<<NTOK / 4, 256, 0, stream>>>(x, pbuf, PS, b2 + (l - 1) * EE,
                                                  ln1g + l * EE, ln1b + l * EE, h);
    gemm_nt<0><<<dim3(16, 24, 1), 256, 0, stream>>>(
        h, WqkvT_all + (size_t)l * 3 * EE * EE, qkv, nullptr,
        EE, EE, EE, 3 * EE, 0);
    transpose_to_bf16<u16><<<dim3(2, 32, 32), 256, 0, stream>>>(
        qkv + 2 * EE, (long)TT * 3 * EE, 64, 16, 3 * EE,
        vT, (long)DK * TT, TT, TT, DK);
    flash_attn_k<<<dim3(16, 32), 256, 0, stream>>>(qkv, vT, o);
    gemm_nt<4><<<dim3(16, 8, 2), 256, 0, stream>>>(
        o, WpT_all + (size_t)l * EE * EE, pbuf, nullptr,
        512, EE, EE, EE, PS);
    ln_fused_k<2><<<NTOK / 4, 256, 0, stream>>>(x, pbuf, PS, bp + l * EE,
                                                ln2g + l * EE, ln2b + l * EE, h);
    const u16* w1t = hoist ? (W1T_all + (size_t)l * FF * EE) : W1T;
    if (!hoist)
      transpose_to_bf16<float><<<dim3(FF / 32, EE / 32, 1), 256, 0, stream>>>(
          W1 + (size_t)l * EE * FF, 0, 0, 1, FF, W1T, 0, EE, EE, FF);
    gemm_nt<2><<<dim3(16, 32, 1), 256, 0, stream>>>(
        h, w1t, mid, b1 + l * FF,
        EE, EE, EE, FF, 0);
    const u16* w2t = hoist ? (W2T_all + (size_t)l * EE * FF) : W2T;
    if (!hoist)
      transpose_to_bf16<float><<<dim3(EE / 32, FF / 32, 1), 256, 0, stream>>>(
          W2 + (size_t)l * FF * EE, 0, 0, 1, EE, W2T, 0, FF, FF, EE);
    gemm_nt<4><<<dim3(16, 8, 4), 256, 0, stream>>>(
        mid, w2t, pbuf, nullptr,
        1024, FF, FF, EE, PS);
  }

  ln_fused_k<4><<<NTOK / 4, 256, 0, stream>>>(x, pbuf, PS, b2 + 5 * EE, lnfg, lnfb, h);
  u16* WoutT = big;
  transpose_to_bf16<float><<<dim3(VV / 32, EE / 32, 1), 256, 0, stream>>>(
      Wout, 0, 0, 1, VV, WoutT, 0, EE, EE, VV);
  // logits: 256^2 coarse counted-vmcnt GEMM (converged structure), grid 8 x 125
  gemm256_nt<<<dim3(NTOK / 256, VV / 256, 1), 512, 0, stream>>>(
      h, WoutT, (float*)d_out, bout, EE, EE, EE, VV);
}

// Round 15
// 1305.223 us; speedup vs baseline: 1.0235x; 1.0235x over previous
//
#include <hip/hip_runtime.h>
#include <cstdio>
#include <cstdint>

typedef unsigned short u16;
typedef __bf16 bf16x8 __attribute__((ext_vector_type(8)));
typedef float f32x4 __attribute__((ext_vector_type(4)));

// problem constants
static const int EE = 1024;   // embed
static const int TT = 1024;   // seq len
static const int BB = 2;      // batch
static const int NTOK = 2048; // B*T
static const int HH = 16;     // heads
static const int DK = 64;
static const int FF = 4096;
static const int VV = 32000;
static const int LL = 6;

__device__ __forceinline__ float bf2f(u16 u) {
  unsigned int i = ((unsigned int)u) << 16;
  float f; __builtin_memcpy(&f, &i, 4); return f;
}
__device__ __forceinline__ u16 f2bf(float f) {
  unsigned int i; __builtin_memcpy(&i, &f, 4);
  unsigned int r = i + 0x7fffu + ((i >> 16) & 1u);
  return (u16)(r >> 16);
}

__device__ __forceinline__ void gll16(const u16* g, u16* l) {
  __builtin_amdgcn_global_load_lds(
      (__attribute__((address_space(1))) void*)(uintptr_t)g,
      (__attribute__((address_space(3))) void*)l,
      16, 0, 0);
}

// ---------------- fused embed + first layernorm ----------------
__global__ __launch_bounds__(256) void embed_ln_k(const int* __restrict__ idx,
                                                  const float* __restrict__ emb,
                                                  const float* __restrict__ pos,
                                                  float* __restrict__ x,
                                                  const float* __restrict__ g,
                                                  const float* __restrict__ b,
                                                  u16* __restrict__ out) {
  int row = blockIdx.x * 4 + (threadIdx.x >> 6);
  int lane = threadIdx.x & 63;
  long base = (long)row * EE;
  int tok = idx[row];
  int t = row & (TT - 1);
  const float* er = emb + (long)tok * EE;
  const float* pr = pos + (long)t * EE;
  float v[16];
  float s = 0.f, s2 = 0.f;
#pragma unroll
  for (int j = 0; j < 16; j++) {
    int c = j * 64 + lane;
    float tv = er[c] + pr[c];
    x[base + c] = tv;
    v[j] = tv; s += tv; s2 += tv * tv;
  }
#pragma unroll
  for (int o = 32; o; o >>= 1) { s += __shfl_xor(s, o); s2 += __shfl_xor(s2, o); }
  float mu = s * (1.f / EE);
  float var = s2 * (1.f / EE) - mu * mu;
  float rs = rsqrtf(var + 1e-5f);
  u16* orow = out + base;
#pragma unroll
  for (int j = 0; j < 16; j++) {
    int c = j * 64 + lane;
    orow[c] = f2bf((v[j] - mu) * rs * g[c] + b[c]);
  }
}

// ---------------- fused residual-reduce + layernorm (bf16 partials) ----------------
template <int NS>
__global__ __launch_bounds__(256) void ln_fused_k(float* __restrict__ x,
                                                  const u16* __restrict__ part, long pstride,
                                                  const float* __restrict__ bias,
                                                  const float* __restrict__ g,
                                                  const float* __restrict__ b,
                                                  u16* __restrict__ out) {
  int row = blockIdx.x * 4 + (threadIdx.x >> 6);
  int lane = threadIdx.x & 63;
  long base = (long)row * EE;
  float v[16];
  float s = 0.f, s2 = 0.f;
#pragma unroll
  for (int j = 0; j < 16; j++) {
    int c = j * 64 + lane;
    float t = x[base + c];
    if constexpr (NS > 0) {
      t += bias[c];
#pragma unroll
      for (int p = 0; p < NS; p++) t += bf2f(part[(long)p * pstride + base + c]);
      x[base + c] = t;
    }
    v[j] = t; s += t; s2 += t * t;
  }
#pragma unroll
  for (int o = 32; o; o >>= 1) { s += __shfl_xor(s, o); s2 += __shfl_xor(s2, o); }
  float mu = s * (1.f / EE);
  float var = s2 * (1.f / EE) - mu * mu;
  float rs = rsqrtf(var + 1e-5f);
  u16* orow = out + base;
#pragma unroll
  for (int j = 0; j < 16; j++) {
    int c = j * 64 + lane;
    orow[c] = f2bf((v[j] - mu) * rs * g[c] + b[c]);
  }
}

// ---------------- pack Wq/Wk/Wv (ALL layers) into bf16 B^T [L][3072][1024] ----------------
__global__ __launch_bounds__(256) void pack_qkvT_k(const float* __restrict__ Wq,
                                                   const float* __restrict__ Wk,
                                                   const float* __restrict__ Wv,
                                                   u16* __restrict__ out) {
  int l = blockIdx.y;
  const float* Wq_l = Wq + (size_t)l * HH * EE * DK;
  const float* Wk_l = Wk + (size_t)l * HH * EE * DK;
  const float* Wv_l = Wv + (size_t)l * HH * EE * DK;
  u16* out_l = out + (size_t)l * 3 * EE * EE;
  long base = ((long)blockIdx.x * 256 + threadIdx.x) * 4;
  int c = (int)(base >> 10);
  int e0 = (int)(base & 1023);
  const float* W = (c < 1024) ? Wq_l : (c < 2048 ? Wk_l : Wv_l);
  int cm = c & 1023;
  int hh = cm >> 6, d = cm & 63;
#pragma unroll
  for (int i = 0; i < 4; i++) {
    int e = e0 + i;
    out_l[(long)c * EE + e] = f2bf(W[((long)hh * EE + e) * DK + d]);
  }
}

// ---------------- batched transpose: src[R,C] (f32 or bf16) -> bf16 dst[C,R] ----------------
template <typename ST>
__global__ __launch_bounds__(256) void transpose_to_bf16(const ST* __restrict__ src,
                                                         long s_z1, long s_z2, int zmod, int ld_s,
                                                         u16* __restrict__ dst,
                                                         long d_z, int ld_d, int R, int C) {
  __shared__ u16 t[32][33];
  int z = blockIdx.z;
  const ST* S = src + (z / zmod) * s_z1 + (z % zmod) * s_z2;
  u16* D = dst + (long)z * d_z;
  int c0 = blockIdx.x * 32, r0 = blockIdx.y * 32;
  int lx = threadIdx.x & 31, ly = threadIdx.x >> 5;
#pragma unroll
  for (int i = 0; i < 4; i++) {
    int r = r0 + ly + i * 8;
    ST val = S[(long)r * ld_s + c0 + lx];
    if constexpr (sizeof(ST) == 4) t[ly + i * 8][lx] = f2bf((float)val);
    else t[ly + i * 8][lx] = (u16)val;
  }
  __syncthreads();
#pragma unroll
  for (int i = 0; i < 4; i++) {
    int c = c0 + ly + i * 8;
    D[(long)c * ld_d + r0 + lx] = t[lx][ly + i * 8];
  }
}

// ---------------- fused flash attention, balanced causal (paired, R13-best) ----------------
// grid (8, 32), 256 thr. Block k handles q-tiles {k, 15-k} (64 rows each, 16 rows/wave)
// -> uniform 17 KV-tile units per block; static pairing beats 512-block split (R14: +27us).
__global__ __launch_bounds__(256) void flash_attn_k(const u16* __restrict__ qkv,
                                                    const u16* __restrict__ vT,
                                                    u16* __restrict__ o) {
  __shared__ u16 Qs[64 * 72];
  __shared__ u16 Ks[2][64 * 72];
  __shared__ u16 Vs[2][64 * 72];
  __shared__ u16 Ps[4][16 * 72];

  int tid = threadIdx.x;
  int lane = tid & 63, w = tid >> 6;
  int fr = lane & 15, kg = lane >> 4;
  int z = blockIdx.y;
  int b = z >> 4, h = z & 15;
  const u16* qbase = qkv + (long)b * TT * 3072 + h * 64;
  const u16* kbase = qbase + 1024;
  const u16* vbase = vT + (long)z * DK * TT;  // [d][t]
  const float scale = 0.03125f;  // 1/sqrt(E)

  for (int p = 0; p < 2; p++) {
    int jq = (p == 0) ? (int)blockIdx.x : 15 - (int)blockIdx.x;
    int q0 = jq * 64;
    int nt = jq + 1;
    if (p) __syncthreads();

    int4 kreg[2], vreg[2];
#pragma unroll
    for (int i = 0; i < 2; i++) {
      int c = i * 256 + tid, row = c >> 3, c8 = c & 7;
      *(int4*)&Qs[row * 72 + c8 * 8] = *(const int4*)(qbase + (long)(q0 + row) * 3072 + c8 * 8);
      kreg[i] = *(const int4*)(kbase + (long)row * 3072 + c8 * 8);
      vreg[i] = *(const int4*)(vbase + (long)row * TT + c8 * 8);
    }
#pragma unroll
    for (int i = 0; i < 2; i++) {
      int c = i * 256 + tid, row = c >> 3, c8 = c & 7;
      *(int4*)&Ks[0][row * 72 + c8 * 8] = kreg[i];
      *(int4*)&Vs[0][row * 72 + c8 * 8] = vreg[i];
    }
    __syncthreads();

    f32x4 zero = {0.f, 0.f, 0.f, 0.f};
    f32x4 acc_o[4];
    float m_i[4], l_i[4];
#pragma unroll
    for (int n = 0; n < 4; n++) acc_o[n] = zero;
#pragma unroll
    for (int r = 0; r < 4; r++) { m_i[r] = -1e30f; l_i[r] = 0.f; }

    for (int t = 0; t < nt; t++) {
      int cur = t & 1;
      int kv0 = t * 64;
      bool pf = (t + 1 < nt);
      if (pf) {
        int kvn = kv0 + 64;
#pragma unroll
        for (int i = 0; i < 2; i++) {
          int c = i * 256 + tid, row = c >> 3, c8 = c & 7;
          kreg[i] = *(const int4*)(kbase + (long)(kvn + row) * 3072 + c8 * 8);
          vreg[i] = *(const int4*)(vbase + (long)row * TT + kvn + c8 * 8);
        }
      }

      f32x4 s[4];
#pragma unroll
      for (int n = 0; n < 4; n++) s[n] = zero;
      {
        bf16x8 aq[2], bk[4][2];
#pragma unroll
        for (int kk = 0; kk < 2; kk++)
          aq[kk] = *(const bf16x8*)&Qs[(w * 16 + fr) * 72 + kk * 32 + kg * 8];
#pragma unroll
        for (int n = 0; n < 4; n++)
#pragma unroll
          for (int kk = 0; kk < 2; kk++)
            bk[n][kk] = *(const bf16x8*)&Ks[cur][(n * 16 + fr) * 72 + kk * 32 + kg * 8];
#pragma unroll
        for (int kk = 0; kk < 2; kk++)
#pragma unroll
          for (int n = 0; n < 4; n++)
            s[n] = __builtin_amdgcn_mfma_f32_16x16x32_bf16(aq[kk], bk[n][kk], s[n], 0, 0, 0);
      }

      float sv[4][4];
#pragma unroll
      for (int n = 0; n < 4; n++)
#pragma unroll
        for (int r = 0; r < 4; r++) {
          int qg = q0 + w * 16 + kg * 4 + r;
          int kgl = kv0 + n * 16 + fr;
          float val = s[n][r] * scale;
          sv[n][r] = (kgl > qg) ? -1e30f : val;
        }
#pragma unroll
      for (int r = 0; r < 4; r++) {
        float rm = fmaxf(fmaxf(sv[0][r], sv[1][r]), fmaxf(sv[2][r], sv[3][r]));
        rm = fmaxf(rm, __shfl_xor(rm, 1));
        rm = fmaxf(rm, __shfl_xor(rm, 2));
        rm = fmaxf(rm, __shfl_xor(rm, 4));
        rm = fmaxf(rm, __shfl_xor(rm, 8));
        float mn = fmaxf(m_i[r], rm);
        float f = __expf(m_i[r] - mn);
        m_i[r] = mn;
        float rs = 0.f;
#pragma unroll
        for (int n = 0; n < 4; n++) {
          float pv = __expf(sv[n][r] - mn);
          sv[n][r] = pv;
          rs += pv;
        }
        rs += __shfl_xor(rs, 1);
        rs += __shfl_xor(rs, 2);
        rs += __shfl_xor(rs, 4);
        rs += __shfl_xor(rs, 8);
        l_i[r] = l_i[r] * f + rs;
#pragma unroll
        for (int n = 0; n < 4; n++) acc_o[n][r] *= f;
      }
#pragma unroll
      for (int n = 0; n < 4; n++)
#pragma unroll
        for (int r = 0; r < 4; r++)
          Ps[w][(kg * 4 + r) * 72 + n * 16 + fr] = f2bf(sv[n][r]);

      {
        bf16x8 pa[2], bv[4][2];
#pragma unroll
        for (int kk = 0; kk < 2; kk++)
          pa[kk] = *(const bf16x8*)&Ps[w][fr * 72 + kk * 32 + kg * 8];
#pragma unroll
        for (int n = 0; n < 4; n++)
#pragma unroll
          for (int kk = 0; kk < 2; kk++)
            bv[n][kk] = *(const bf16x8*)&Vs[cur][(n * 16 + fr) * 72 + kk * 32 + kg * 8];
#pragma unroll
        for (int kk = 0; kk < 2; kk++)
#pragma unroll
          for (int n = 0; n < 4; n++)
            acc_o[n] = __builtin_amdgcn_mfma_f32_16x16x32_bf16(pa[kk], bv[n][kk], acc_o[n], 0, 0, 0);
      }

      if (pf) {
#pragma unroll
        for (int i = 0; i < 2; i++) {
          int c = i * 256 + tid, row = c >> 3, c8 = c & 7;
          *(int4*)&Ks[cur ^ 1][row * 72 + c8 * 8] = kreg[i];
          *(int4*)&Vs[cur ^ 1][row * 72 + c8 * 8] = vreg[i];
        }
      }
      __syncthreads();
    }

    u16* obase = o + ((long)b * TT + q0) * EE + h * 64;
#pragma unroll
    for (int r = 0; r < 4; r++) {
      float inv = 1.f / l_i[r];
      int qrow = w * 16 + kg * 4 + r;
#pragma unroll
      for (int n = 0; n < 4; n++)
        obase[(long)qrow * EE + n * 16 + fr] = f2bf(acc_o[n][r] * inv);
    }
  }
}

// ---------------- 128x128 NT GEMM, double-buffered counted-vmcnt pipeline ----------------
// EPI: 0 = bf16 C=acc ; 1 = fp32 C=acc+bias ; 2 = bf16 C=relu(acc+bias) ;
//      4 = bf16 C=acc (split-K partial at blockIdx.z * c_zs)
template <int EPI>
__global__ __launch_bounds__(256) void gemm_nt(
    const u16* __restrict__ A, const u16* __restrict__ BT, void* Cv,
    const float* __restrict__ bias,
    int Kc, int lda, int ldb, int ldc, long c_zs) {
  constexpr int BK = 64;
  __shared__ u16 As[2][128 * BK];
  __shared__ u16 Bs[2][128 * BK];

  int m0 = blockIdx.x * 128, n0 = blockIdx.y * 128;
  int z = blockIdx.z;
  int tid = threadIdx.x, lane = tid & 63, wave = tid >> 6;
  int wm = wave >> 1, wn = wave & 1;
  int fr = lane & 15, kg = lane >> 4;
  int xk0 = ((kg) ^ (fr & 7)) * 8;
  int xk1 = ((4 + kg) ^ (fr & 7)) * 8;
  int kbeg = z * Kc;

  auto STAGE = [&](int t, int b) {
    int k0 = kbeg + t * BK;
#pragma unroll
    for (int i = 0; i < 4; i++) {
      int c = i * 256 + tid, row = c >> 3;
      int ch = (c & 7) ^ (row & 7);  // pre-swizzled global source (rule #21)
      gll16(A + (long)(m0 + row) * lda + k0 + ch * 8, &As[b][c * 8]);
      gll16(BT + (long)(n0 + row) * ldb + k0 + ch * 8, &Bs[b][c * 8]);
    }
  };

  f32x4 zero = {0.f, 0.f, 0.f, 0.f};
  f32x4 acc[4][4];
#pragma unroll
  for (int m = 0; m < 4; m++)
#pragma unroll
    for (int n = 0; n < 4; n++) acc[m][n] = zero;

  int NT = Kc / BK;
  STAGE(0, 0);
  if (NT > 1) STAGE(1, 1);

  for (int c = 0; c < NT; c++) {
    if (c + 1 < NT) asm volatile("s_waitcnt vmcnt(8)" ::: "memory");
    else            asm volatile("s_waitcnt vmcnt(0)" ::: "memory");
    __builtin_amdgcn_s_barrier();
    const u16* Ab = As[c & 1];
    const u16* Bb = Bs[c & 1];
#pragma unroll
    for (int kk = 0; kk < 2; kk++) {
      int xo = kk ? xk1 : xk0;
      bf16x8 af[4], bf[4];
#pragma unroll
      for (int m = 0; m < 4; m++)
        af[m] = *(const bf16x8*)&Ab[(wm * 64 + m * 16 + fr) * BK + xo];
#pragma unroll
      for (int n = 0; n < 4; n++)
        bf[n] = *(const bf16x8*)&Bb[(wn * 64 + n * 16 + fr) * BK + xo];
      __builtin_amdgcn_s_setprio(1);
#pragma unroll
      for (int m = 0; m < 4; m++)
#pragma unroll
        for (int n = 0; n < 4; n++)
          acc[m][n] = __builtin_amdgcn_mfma_f32_16x16x32_bf16(af[m], bf[n], acc[m][n], 0, 0, 0);
      __builtin_amdgcn_s_setprio(0);
    }
    __builtin_amdgcn_s_barrier();
    if (c + 2 < NT) STAGE(c + 2, c & 1);
  }

  u16* C16 = (u16*)Cv;
  float* C32 = (float*)Cv;
  long cb = (long)z * c_zs;
  int rowb = m0 + wm * 64, colb = n0 + wn * 64;
#pragma unroll
  for (int m = 0; m < 4; m++) {
#pragma unroll
    for (int n = 0; n < 4; n++) {
      int gc = colb + n * 16 + fr;
      float bv = 0.f;
      if (EPI == 1 || EPI == 2) bv = bias[gc];
#pragma unroll
      for (int r = 0; r < 4; r++) {
        int gr = rowb + m * 16 + kg * 4 + r;
        long ci = cb + (long)gr * ldc + gc;
        float val = acc[m][n][r];
        if (EPI == 0) C16[ci] = f2bf(val);
        else if (EPI == 1) C32[ci] = val + bv;
        else if (EPI == 2) C16[ci] = f2bf(fmaxf(val + bv, 0.f));
        else C16[ci] = f2bf(val);  // EPI 4: bf16 split-K partial
      }
    }
  }
}

// ---------------- 256x256 NT GEMM, 8 waves, coarse counted-vmcnt (R5, converged best) ----------------
// Structure ledger (all refcheck'd on this problem): coarse+vmcnt(8)=183-189us;
// 8-phase variants=194-198; nt-stores=216; 3-stage 256x128 ring=244. Keep coarse.
__global__ __launch_bounds__(512) void gemm256_nt(
    const u16* __restrict__ A, const u16* __restrict__ BT,
    float* __restrict__ C, const float* __restrict__ bias,
    int K, int lda, int ldb, int ldc) {
  __shared__ u16 lds[2][2][256 * 64];

  int tid = threadIdx.x, lane = tid & 63, wave = tid >> 6;
  int wm = wave >> 2, wn = wave & 3;
  int fr = lane & 15, kg = lane >> 4;
  int m0 = blockIdx.x * 256, n0 = blockIdx.y * 256;

  auto STAGE = [&](int t, int b) {
    int k0 = t * 64;
#pragma unroll
    for (int r = 0; r < 4; r++) {
      int g = r * 512 + tid;
      int row = g >> 3, cl = (g & 7) ^ (row & 7);
      gll16(A + (long)(m0 + row) * lda + k0 + cl * 8, &lds[b][0][g * 8]);
    }
#pragma unroll
    for (int r = 0; r < 4; r++) {
      int g = r * 512 + tid;
      int row = g >> 3, cl = (g & 7) ^ (row & 7);
      gll16(BT + (long)(n0 + row) * ldb + k0 + cl * 8, &lds[b][1][g * 8]);
    }
  };

  f32x4 zero = {0.f, 0.f, 0.f, 0.f};
  f32x4 acc[8][4];
#pragma unroll
  for (int m = 0; m < 8; m++)
#pragma unroll
    for (int n = 0; n < 4; n++) acc[m][n] = zero;

  int NT = K / 64;
  STAGE(0, 0);
  if (NT > 1) STAGE(1, 1);

  for (int c = 0; c < NT; c++) {
    if (c + 1 < NT) asm volatile("s_waitcnt vmcnt(8)" ::: "memory");
    else            asm volatile("s_waitcnt vmcnt(0)" ::: "memory");
    __builtin_amdgcn_s_barrier();
    const u16* Ab = lds[c & 1][0];
    const u16* Bb = lds[c & 1][1];
#pragma unroll
    for (int ph = 0; ph < 4; ph++) {
      int mh = ph >> 1, nh = ph & 1;
      bf16x8 af[4][2], bf[2][2];
#pragma unroll
      for (int m = 0; m < 4; m++) {
        int row = wm * 128 + mh * 64 + m * 16 + fr;
#pragma unroll
        for (int kk = 0; kk < 2; kk++) {
          int cp = (kk * 4 + kg) ^ (row & 7);
          af[m][kk] = *(const bf16x8*)&Ab[row * 64 + cp * 8];
        }
      }
#pragma unroll
      for (int n = 0; n < 2; n++) {
        int row = wn * 64 + nh * 32 + n * 16 + fr;
#pragma unroll
        for (int kk = 0; kk < 2; kk++) {
          int cp = (kk * 4 + kg) ^ (row & 7);
          bf[n][kk] = *(const bf16x8*)&Bb[row * 64 + cp * 8];
        }
      }
      __builtin_amdgcn_s_setprio(1);
#pragma unroll
      for (int kk = 0; kk < 2; kk++)
#pragma unroll
        for (int m = 0; m < 4; m++)
#pragma unroll
          for (int n = 0; n < 2; n++)
            acc[mh * 4 + m][nh * 2 + n] = __builtin_amdgcn_mfma_f32_16x16x32_bf16(
                af[m][kk], bf[n][kk], acc[mh * 4 + m][nh * 2 + n], 0, 0, 0);
      __builtin_amdgcn_s_setprio(0);
    }
    __builtin_amdgcn_s_barrier();
    if (c + 2 < NT) STAGE(c + 2, c & 1);
  }

  // epilogue: fp32 + bias (plain stores — nt stores measured WORSE, R8)
  int rowb = m0 + wm * 128, colb = n0 + wn * 64;
#pragma unroll
  for (int m = 0; m < 8; m++) {
#pragma unroll
    for (int n = 0; n < 4; n++) {
      int gc = colb + n * 16 + fr;
      float bv = bias[gc];
#pragma unroll
      for (int r = 0; r < 4; r++) {
        int gr = rowb + m * 16 + kg * 4 + r;
        C[(long)gr * ldc + gc] = acc[m][n][r] + bv;
      }
    }
  }
}

extern "C" void kernel_launch(void* const* d_in, const int* in_sizes, int n_in,
                              void* d_out, int out_size, void* d_ws, size_t ws_size,
                              hipStream_t stream) {
  const int*   idx  = (const int*)d_in[0];
  const float* emb  = (const float*)d_in[1];
  const float* pos  = (const float*)d_in[2];
  const float* Wq   = (const float*)d_in[3];
  const float* Wk   = (const float*)d_in[4];
  const float* Wv   = (const float*)d_in[5];
  const float* Wp   = (const float*)d_in[6];
  const float* bp   = (const float*)d_in[7];
  const float* ln1g = (const float*)d_in[8];
  const float* ln1b = (const float*)d_in[9];
  const float* ln2g = (const float*)d_in[10];
  const float* ln2b = (const float*)d_in[11];
  const float* W1   = (const float*)d_in[12];
  const float* b1   = (const float*)d_in[13];
  const float* W2   = (const float*)d_in[14];
  const float* b2   = (const float*)d_in[15];
  const float* lnfg = (const float*)d_in[16];
  const float* lnfb = (const float*)d_in[17];
  const float* Wout = (const float*)d_in[18];
  const float* bout = (const float*)d_in[19];

  char* w = (char*)d_ws;
  size_t off = 0;
  auto alloc = [&](size_t bytes) {
    void* p = w + off;
    off += (bytes + 255) & ~(size_t)255;
    return p;
  };
  float* x    = (float*)alloc((size_t)NTOK * EE * 4);
  u16* h      = (u16*)alloc((size_t)NTOK * EE * 2);
  u16* qkv    = (u16*)alloc((size_t)NTOK * 3 * EE * 2);
  u16* vT     = (u16*)alloc((size_t)BB * HH * DK * TT * 2);
  u16* big    = (u16*)alloc((size_t)VV * EE * 2);
  u16* o      = (u16*)alloc((size_t)NTOK * EE * 2);
  u16* mid    = (u16*)alloc((size_t)NTOK * FF * 2);
  u16* W1T    = (u16*)alloc((size_t)FF * EE * 2);
  u16* W2T    = (u16*)alloc((size_t)EE * FF * 2);
  u16* pbuf   = (u16*)alloc((size_t)4 * NTOK * EE * 2);  // bf16 split-K partials
  if (off > ws_size) {
    fprintf(stderr, "kernel_launch: ws too small, need %zu have %zu\n", off, ws_size);
    return;
  }
  // optional hoisted per-layer MLP weight transposes (fallback if ws too small)
  size_t off_saved = off;
  u16* W1T_all = (u16*)alloc((size_t)LL * FF * EE * 2);
  u16* W2T_all = (u16*)alloc((size_t)LL * EE * FF * 2);
  bool hoist = (off <= ws_size);
  if (!hoist) off = off_saved;

  u16* WqkvT_all = big;                            // [6][3072][1024] = 36 MB
  u16* WpT_all   = big + (size_t)6 * 3 * EE * EE;  // [6][1024][1024] = 12 MB
  const long PS = (long)NTOK * EE;

  // fused embed + LN(layer 0)
  embed_ln_k<<<NTOK / 4, 256, 0, stream>>>(idx, emb, pos, x, ln1g, ln1b, h);
  pack_qkvT_k<<<dim3(3 * EE * EE / 1024, LL), 256, 0, stream>>>(Wq, Wk, Wv, WqkvT_all);
  transpose_to_bf16<float><<<dim3(32, 32, LL), 256, 0, stream>>>(
      Wp, (long)EE * EE, 0, 1, EE, WpT_all, (long)EE * EE, EE, EE, EE);
  if (hoist) {
    transpose_to_bf16<float><<<dim3(FF / 32, EE / 32, LL), 256, 0, stream>>>(
        W1, (long)EE * FF, 0, 1, FF, W1T_all, (long)FF * EE, EE, EE, FF);
    transpose_to_bf16<float><<<dim3(EE / 32, FF / 32, LL), 256, 0, stream>>>(
        W2, (long)FF * EE, 0, 1, EE, W2T_all, (long)EE * FF, FF, FF, EE);
  }

  for (int l = 0; l < LL; l++) {
    if (l > 0)
      ln_fused_k<4><<<NTOK / 4, 256, 0, stream>>>(x, pbuf, PS, b2 + (l - 1) * EE,
                                                  ln1g + l * EE, ln1b + l * EE, h);
    gemm_nt<0><<<dim3(16, 24, 1), 256, 0, stream>>>(
        h, WqkvT_all + (size_t)l * 3 * EE * EE, qkv, nullptr,
        EE, EE, EE, 3 * EE, 0);
    transpose_to_bf16<u16><<<dim3(2, 32, 32), 256, 0, stream>>>(
        qkv + 2 * EE, (long)TT * 3 * EE, 64, 16, 3 * EE,
        vT, (long)DK * TT, TT, TT, DK);
    flash_attn_k<<<dim3(8, 32), 256, 0, stream>>>(qkv, vT, o);
    gemm_nt<4><<<dim3(16, 8, 2), 256, 0, stream>>>(
        o, WpT_all + (size_t)l * EE * EE, pbuf, nullptr,
        512, EE, EE, EE, PS);
    ln_fused_k<2><<<NTOK / 4, 256, 0, stream>>>(x, pbuf, PS, bp + l * EE,
                                                ln2g + l * EE, ln2b + l * EE, h);
    const u16* w1t = hoist ? (W1T_all + (size_t)l * FF * EE) : W1T;
    if (!hoist)
      transpose_to_bf16<float><<<dim3(FF / 32, EE / 32, 1), 256, 0, stream>>>(
          W1 + (size_t)l * EE * FF, 0, 0, 1, FF, W1T, 0, EE, EE, FF);
    gemm_nt<2><<<dim3(16, 32, 1), 256, 0, stream>>>(
        h, w1t, mid, b1 + l * FF,
        EE, EE, EE, FF, 0);
    const u16* w2t = hoist ? (W2T_all + (size_t)l * EE * FF) : W2T;
    if (!hoist)
      transpose_to_bf16<float><<<dim3(EE / 32, FF / 32, 1), 256, 0, stream>>>(
          W2 + (size_t)l * FF * EE, 0, 0, 1, EE, W2T, 0, FF, FF, EE);
    gemm_nt<4><<<dim3(16, 8, 4), 256, 0, stream>>>(
        mid, w2t, pbuf, nullptr,
        1024, FF, FF, EE, PS);
  }

  ln_fused_k<4><<<NTOK / 4, 256, 0, stream>>>(x, pbuf, PS, b2 + 5 * EE, lnfg, lnfb, h);
  u16* WoutT = big;
  transpose_to_bf16<float><<<dim3(VV / 32, EE / 32, 1), 256, 0, stream>>>(
      Wout, 0, 0, 1, VV, WoutT, 0, EE, EE, VV);
  // logits: 256^2 coarse counted-vmcnt GEMM (converged structure), grid 8 x 125
  gemm256_nt<<<dim3(NTOK / 256, VV / 256, 1), 512, 0, stream>>>(
      h, WoutT, (float*)d_out, bout, EE, EE, EE, VV);
}